// Round 1
// baseline (827.501 us; speedup 1.0000x reference)
//
#include <hip/hip_runtime.h>

// TransformerBlock on MI355X (gfx950) — round 0: correctness-first bf16-MFMA build.
// B=4 S=2048 D=1024 H=16 DK=64 DFF=4096. fp32 in/out, bf16 tensor-core compute.

typedef unsigned short u16;
typedef __attribute__((ext_vector_type(8))) short short8;   // 8 bf16 = 4 VGPRs (MFMA A/B frag)
typedef __attribute__((ext_vector_type(4))) float f32x4;    // MFMA C/D frag

#define MFMA16(a, b, c) __builtin_amdgcn_mfma_f32_16x16x32_bf16(a, b, c, 0, 0, 0)

__device__ __forceinline__ u16 f2b(float f) {
  union { float f; unsigned u; } x; x.f = f;
  unsigned r = x.u + 0x7FFFu + ((x.u >> 16) & 1u);   // RNE
  return (u16)(r >> 16);
}
__device__ __forceinline__ float b2f(u16 h) {
  union { unsigned u; float f; } x; x.u = ((unsigned)h) << 16;
  return x.f;
}
// async global->LDS, 16B per lane. LDS dest is wave-uniform base + lane*16 --
// lane l of the issuing wave must pass ldsptr = base + l*16 (guide §5 caveat).
__device__ __forceinline__ void async16(const void* g, void* l) {
  __builtin_amdgcn_global_load_lds(
      (const __attribute__((address_space(1))) void*)g,
      (__attribute__((address_space(3))) void*)l, 16, 0, 0);
}

// ---------------------------------------------------------------------------
// GEMM (bt-form): C[m,n] = sum_k A[m,k]*B[n,k].  A: MxK bf16, B: NxK bf16.
// 128x128 tile, BK=64, 256 thr = 4 waves (2x2 of 64x64), 16x16x32 bf16 MFMA.
// LDS chunk-XOR swizzle: element [r][k] lives at chunk (k/8)^(r&7) so the
// ds_read_b128 fragment reads are bank-conflict-free.
// MODE 0: store bf16 C.  MODE 1: store fp32 C + residual R.
// ---------------------------------------------------------------------------
template <int MODE>
__global__ __launch_bounds__(256) void gemm_bt(
    const u16* __restrict__ A, const u16* __restrict__ B,
    u16* __restrict__ Cb, float* __restrict__ Cf, const float* __restrict__ R,
    int M, int N, int K) {
  __shared__ __align__(16) u16 As[128 * 64];
  __shared__ __align__(16) u16 Bs[128 * 64];
  const int tid = threadIdx.x;
  const int l = tid & 63, w = tid >> 6;
  const int wr = w & 1, wc = w >> 1;
  const int lrow = l & 15, lq = l >> 4;
  const size_t m0 = (size_t)blockIdx.y * 128, n0 = (size_t)blockIdx.x * 128;
  f32x4 acc[4][4] = {};
  for (int k0 = 0; k0 < K; k0 += 64) {
#pragma unroll
    for (int t = 0; t < 4; ++t) {  // 128x64 bf16 = 8KB = 512 chunks of 16B
      int c = t * 256 + tid;
      int r = c >> 3;
      int gc = ((c & 7) ^ (r & 7)) << 3;
      async16(A + (m0 + r) * (size_t)K + k0 + gc, &As[c * 8]);
    }
#pragma unroll
    for (int t = 0; t < 4; ++t) {
      int c = t * 256 + tid;
      int r = c >> 3;
      int gc = ((c & 7) ^ (r & 7)) << 3;
      async16(B + (n0 + r) * (size_t)K + k0 + gc, &Bs[c * 8]);
    }
    __syncthreads();
#pragma unroll
    for (int kk = 0; kk < 2; ++kk) {
      const int kc = kk * 4 + lq;
      short8 af[4], bfr[4];
#pragma unroll
      for (int mi = 0; mi < 4; ++mi) {
        int r = wr * 64 + mi * 16 + lrow;
        af[mi] = *(const short8*)&As[r * 64 + ((kc ^ (r & 7)) << 3)];
      }
#pragma unroll
      for (int ni = 0; ni < 4; ++ni) {
        int r = wc * 64 + ni * 16 + lrow;
        bfr[ni] = *(const short8*)&Bs[r * 64 + ((kc ^ (r & 7)) << 3)];
      }
#pragma unroll
      for (int mi = 0; mi < 4; ++mi)
#pragma unroll
        for (int ni = 0; ni < 4; ++ni)
          acc[mi][ni] = MFMA16(af[mi], bfr[ni], acc[mi][ni]);
    }
    __syncthreads();
  }
  // epilogue: C/D layout col = lane&15, row = (lane>>4)*4 + reg (m89/m91)
#pragma unroll
  for (int mi = 0; mi < 4; ++mi)
#pragma unroll
    for (int ni = 0; ni < 4; ++ni) {
      size_t n = n0 + wc * 64 + ni * 16 + lrow;
#pragma unroll
      for (int r4 = 0; r4 < 4; ++r4) {
        size_t m = m0 + wr * 64 + mi * 16 + lq * 4 + r4;
        float v = acc[mi][ni][r4];
        if (MODE == 0)
          Cb[m * (size_t)N + n] = f2b(v);
        else
          Cf[m * (size_t)N + n] = v + R[m * (size_t)N + n];
      }
    }
}

// ---------------------------------------------------------------------------
// Fused SwiGLU GEMM: h = silu(A@W1^T) * (A@W3^T), bf16 out. Same structure,
// two B tiles + two accumulator sets.
// ---------------------------------------------------------------------------
__global__ __launch_bounds__(256) void ffn_gemm(
    const u16* __restrict__ A, const u16* __restrict__ B1,
    const u16* __restrict__ B3, u16* __restrict__ Hout, int M, int N, int K) {
  __shared__ __align__(16) u16 As[128 * 64];
  __shared__ __align__(16) u16 B1s[128 * 64];
  __shared__ __align__(16) u16 B3s[128 * 64];
  const int tid = threadIdx.x;
  const int l = tid & 63, w = tid >> 6;
  const int wr = w & 1, wc = w >> 1;
  const int lrow = l & 15, lq = l >> 4;
  const size_t m0 = (size_t)blockIdx.y * 128, n0 = (size_t)blockIdx.x * 128;
  f32x4 a1[4][4] = {}, a3[4][4] = {};
  for (int k0 = 0; k0 < K; k0 += 64) {
#pragma unroll
    for (int t = 0; t < 4; ++t) {
      int c = t * 256 + tid;
      int r = c >> 3;
      int gc = ((c & 7) ^ (r & 7)) << 3;
      async16(A + (m0 + r) * (size_t)K + k0 + gc, &As[c * 8]);
      async16(B1 + (n0 + r) * (size_t)K + k0 + gc, &B1s[c * 8]);
      async16(B3 + (n0 + r) * (size_t)K + k0 + gc, &B3s[c * 8]);
    }
    __syncthreads();
#pragma unroll
    for (int kk = 0; kk < 2; ++kk) {
      const int kc = kk * 4 + lq;
      short8 af[4], b1f[4], b3f[4];
#pragma unroll
      for (int mi = 0; mi < 4; ++mi) {
        int r = wr * 64 + mi * 16 + lrow;
        af[mi] = *(const short8*)&As[r * 64 + ((kc ^ (r & 7)) << 3)];
      }
#pragma unroll
      for (int ni = 0; ni < 4; ++ni) {
        int r = wc * 64 + ni * 16 + lrow;
        b1f[ni] = *(const short8*)&B1s[r * 64 + ((kc ^ (r & 7)) << 3)];
        b3f[ni] = *(const short8*)&B3s[r * 64 + ((kc ^ (r & 7)) << 3)];
      }
#pragma unroll
      for (int mi = 0; mi < 4; ++mi)
#pragma unroll
        for (int ni = 0; ni < 4; ++ni) {
          a1[mi][ni] = MFMA16(af[mi], b1f[ni], a1[mi][ni]);
          a3[mi][ni] = MFMA16(af[mi], b3f[ni], a3[mi][ni]);
        }
    }
    __syncthreads();
  }
#pragma unroll
  for (int mi = 0; mi < 4; ++mi)
#pragma unroll
    for (int ni = 0; ni < 4; ++ni) {
      size_t n = n0 + wc * 64 + ni * 16 + lrow;
#pragma unroll
      for (int r4 = 0; r4 < 4; ++r4) {
        size_t m = m0 + wr * 64 + mi * 16 + lq * 4 + r4;
        float u = a1[mi][ni][r4];
        float g = u / (1.0f + __expf(-u));  // silu
        Hout[m * (size_t)N + n] = f2b(g * a3[mi][ni][r4]);
      }
    }
}

// ---------------------------------------------------------------------------
// Flash attention (causal). One block = 64 q-rows (4 waves x 16), loop over
// 64-wide KV tiles. qh/kh: [b][h][s][64] bf16 (RoPE'd). vt: [b][h][64][s].
// q0,kv0 are 64-aligned => only the kv0==q0 tile needs masking, and every
// row always has >=1 unmasked col (no NaN path with finite -1e30 mask).
// ---------------------------------------------------------------------------
__global__ __launch_bounds__(256) void attn_k(
    const u16* __restrict__ qh, const u16* __restrict__ kh,
    const u16* __restrict__ vt, u16* __restrict__ aout) {
  __shared__ __align__(16) u16 Ks[64 * 64];
  __shared__ __align__(16) u16 Vs[64 * 64];        // vT tile: rows d, cols kc
  __shared__ __align__(16) u16 Ps[4][16 * 72];     // per-wave P, stride 72 (144B, 16B-mult)
  const int tid = threadIdx.x;
  const int l = tid & 63, w = tid >> 6;
  const int lrow = l & 15, lq = l >> 4;
  const int q0 = blockIdx.x * 64;
  const int bh = blockIdx.y;
  const size_t base = (size_t)bh * (2048 * 64);

  short8 aq[2];
  const int qrow = q0 + w * 16 + lrow;
#pragma unroll
  for (int kk = 0; kk < 2; ++kk)
    aq[kk] = *(const short8*)(qh + base + (size_t)qrow * 64 + kk * 32 + lq * 8);

  f32x4 o[4] = {};
  float mI[4], lI[4];
#pragma unroll
  for (int r = 0; r < 4; ++r) { mI[r] = -1e30f; lI[r] = 0.0f; }

  for (int kv0 = 0; kv0 <= q0; kv0 += 64) {
#pragma unroll
    for (int t = 0; t < 2; ++t) {  // 64x64 bf16 = 8KB = 512 chunks, 2/thread
      int c = t * 256 + tid;
      int r = c >> 3;
      int gc = ((c & 7) ^ (r & 7)) << 3;
      async16(kh + base + (size_t)(kv0 + r) * 64 + gc, &Ks[c * 8]);
      async16(vt + base + (size_t)r * 2048 + kv0 + gc, &Vs[c * 8]);
    }
    __syncthreads();
    // scores: S[16 x 64] per wave
    f32x4 s[4] = {};
#pragma unroll
    for (int kk = 0; kk < 2; ++kk) {
      const int kc = kk * 4 + lq;
#pragma unroll
      for (int ni = 0; ni < 4; ++ni) {
        int r = ni * 16 + lrow;
        short8 bk = *(const short8*)&Ks[r * 64 + ((kc ^ (r & 7)) << 3)];
        s[ni] = MFMA16(aq[kk], bk, s[ni]);
      }
    }
    const bool diag = (kv0 == q0);
#pragma unroll
    for (int ni = 0; ni < 4; ++ni)
#pragma unroll
      for (int r = 0; r < 4; ++r) {
        float v = s[ni][r] * 0.125f;  // 1/sqrt(64)
        if (diag && (kv0 + ni * 16 + lrow > q0 + w * 16 + lq * 4 + r)) v = -1e30f;
        s[ni][r] = v;
      }
    // online softmax: row r lives in the 16 lanes of group lq, reg r&3
    float al[4];
#pragma unroll
    for (int r = 0; r < 4; ++r) {
      float mx = fmaxf(fmaxf(s[0][r], s[1][r]), fmaxf(s[2][r], s[3][r]));
#pragma unroll
      for (int d = 1; d < 16; d <<= 1) mx = fmaxf(mx, __shfl_xor(mx, d, 64));
      float mn = fmaxf(mI[r], mx);
      al[r] = __expf(mI[r] - mn);
      mI[r] = mn;
    }
    float rs[4] = {0.f, 0.f, 0.f, 0.f};
#pragma unroll
    for (int ni = 0; ni < 4; ++ni)
#pragma unroll
      for (int r = 0; r < 4; ++r) {
        float p = __expf(s[ni][r] - mI[r]);
        s[ni][r] = p;
        rs[r] += p;
      }
#pragma unroll
    for (int r = 0; r < 4; ++r) {
#pragma unroll
      for (int d = 1; d < 16; d <<= 1) rs[r] += __shfl_xor(rs[r], d, 64);
      lI[r] = lI[r] * al[r] + rs[r];
    }
#pragma unroll
    for (int ni = 0; ni < 4; ++ni)
#pragma unroll
      for (int r = 0; r < 4; ++r) o[ni][r] *= al[r];
    // P -> LDS (C-layout scatter), then re-read as A-fragment
#pragma unroll
    for (int ni = 0; ni < 4; ++ni)
#pragma unroll
      for (int r = 0; r < 4; ++r)
        Ps[w][(lq * 4 + r) * 72 + ni * 16 + lrow] = f2b(s[ni][r]);
    __syncthreads();
#pragma unroll
    for (int kk = 0; kk < 2; ++kk) {
      const int kc = kk * 4 + lq;
      short8 ap = *(const short8*)&Ps[w][lrow * 72 + kk * 32 + lq * 8];
#pragma unroll
      for (int ni = 0; ni < 4; ++ni) {
        int r = ni * 16 + lrow;
        short8 bv = *(const short8*)&Vs[r * 64 + ((kc ^ (r & 7)) << 3)];
        o[ni] = MFMA16(ap, bv, o[ni]);
      }
    }
    __syncthreads();
  }
  const int b = bh >> 4, h = bh & 15;
#pragma unroll
  for (int ni = 0; ni < 4; ++ni)
#pragma unroll
    for (int r = 0; r < 4; ++r) {
      int row = q0 + w * 16 + lq * 4 + r;
      int d = ni * 16 + lrow;
      aout[((size_t)(b * 2048 + row)) * 1024 + h * 64 + d] = f2b(o[ni][r] / lI[r]);
    }
}

// ---------------------------------------------------------------------------
// Elementwise helpers
// ---------------------------------------------------------------------------
__global__ __launch_bounds__(256) void rmsnorm_k(
    const float* __restrict__ x, const float* __restrict__ w, u16* __restrict__ out) {
  const int row = blockIdx.x;
  const int tid = threadIdx.x;
  const float4 v = ((const float4*)(x + (size_t)row * 1024))[tid];
  float ss = v.x * v.x + v.y * v.y + v.z * v.z + v.w * v.w;
#pragma unroll
  for (int d = 1; d < 64; d <<= 1) ss += __shfl_xor(ss, d, 64);
  __shared__ float red[4];
  if ((tid & 63) == 0) red[tid >> 6] = ss;
  __syncthreads();
  const float sc = rsqrtf((red[0] + red[1] + red[2] + red[3]) * (1.0f / 1024.0f) + 1e-5f);
  const float4 wv = ((const float4*)w)[tid];
  u16* o = out + (size_t)row * 1024 + tid * 4;
  o[0] = f2b(v.x * sc * wv.x);
  o[1] = f2b(v.y * sc * wv.y);
  o[2] = f2b(v.z * sc * wv.z);
  o[3] = f2b(v.w * sc * wv.w);
}

// RoPE + [b][s][h*64+d] -> [b][h][s][64] relayout. One thread per pair.
__global__ __launch_bounds__(256) void rope_k(
    const u16* __restrict__ src, u16* __restrict__ dst, const int* __restrict__ pos) {
  int idx = blockIdx.x * 256 + threadIdx.x;  // 8192 rows * 512 pairs
  int pr = idx & 511;
  int row = idx >> 9;
  int s = row & 2047, b = row >> 11;
  int h = pr >> 5, i = pr & 31;
  size_t si = (size_t)row * 1024 + h * 64 + 2 * i;
  float xe = b2f(src[si]), xo = b2f(src[si + 1]);
  // theta^(-2i/64) = 2^(-(2i/64)*log2(10000))
  float inv = exp2f(-(float)(2 * i) * (13.287712379549449f / 64.0f));
  float ang = (float)pos[s] * inv;
  float sn, cs;
  __sincosf(ang, &sn, &cs);
  size_t od = (((size_t)(b * 16 + h)) * 2048 + s) * 64 + 2 * i;
  dst[od] = f2b(xe * cs - xo * sn);
  dst[od + 1] = f2b(xe * sn + xo * cs);
}

// v [b][s][h*64+d] -> vT [b][h][d][s], 64x64 LDS tile transpose
__global__ __launch_bounds__(256) void transv_k(
    const u16* __restrict__ v, u16* __restrict__ vt) {
  __shared__ u16 t[64][65];
  const int bh = blockIdx.y, s0 = blockIdx.x * 64;
  const int b = bh >> 4, h = bh & 15;
  const int tid = threadIdx.x;
#pragma unroll
  for (int i = 0; i < 16; ++i) {
    int e = i * 256 + tid;
    int sl = e >> 6, d = e & 63;
    t[sl][d] = v[((size_t)(b * 2048 + s0 + sl)) * 1024 + h * 64 + d];
  }
  __syncthreads();
#pragma unroll
  for (int i = 0; i < 16; ++i) {
    int e = i * 256 + tid;
    int d = e >> 6, sl = e & 63;
    vt[((size_t)(bh * 64 + d)) * 2048 + s0 + sl] = t[sl][d];
  }
}

__global__ __launch_bounds__(256) void cvt_k(
    const float* __restrict__ in, u16* __restrict__ out, int n4) {
  int i = blockIdx.x * 256 + threadIdx.x;
  if (i < n4) {
    float4 v = ((const float4*)in)[i];
    u16* o = out + (size_t)i * 4;
    o[0] = f2b(v.x); o[1] = f2b(v.y); o[2] = f2b(v.z); o[3] = f2b(v.w);
  }
}

// ---------------------------------------------------------------------------
extern "C" void kernel_launch(void* const* d_in, const int* in_sizes, int n_in,
                              void* d_out, int out_size, void* d_ws, size_t ws_size,
                              hipStream_t stream) {
  const float* x   = (const float*)d_in[0];
  const int*   pos = (const int*)d_in[1];
  const float* qp  = (const float*)d_in[2];
  const float* kp  = (const float*)d_in[3];
  const float* vp  = (const float*)d_in[4];
  const float* op  = (const float*)d_in[5];
  const float* w1  = (const float*)d_in[6];
  const float* w2  = (const float*)d_in[7];   // note: w2 before w3 in dict order
  const float* w3  = (const float*)d_in[8];
  const float* ln1 = (const float*)d_in[9];
  const float* ln2 = (const float*)d_in[10];
  float* out = (float*)d_out;
  char* ws = (char*)d_ws;
  const size_t MB = 1024 * 1024;

  // workspace layout (144 MB total, with aliased lifetimes):
  u16* WQ  = (u16*)(ws + 0 * MB);
  u16* WK  = (u16*)(ws + 2 * MB);
  u16* WV  = (u16*)(ws + 4 * MB);
  u16* WO  = (u16*)(ws + 6 * MB);
  u16* W1  = (u16*)(ws + 8 * MB);
  u16* W3  = (u16*)(ws + 16 * MB);
  u16* W2  = (u16*)(ws + 24 * MB);
  u16* XLN = (u16*)(ws + 32 * MB);   // 16 MB
  u16* Kb  = (u16*)(ws + 48 * MB);   // k row-major; later xln2
  u16* Qb  = (u16*)(ws + 64 * MB);   // q row-major; later attn_out
  u16* Vb  = (u16*)(ws + 80 * MB);   // v row-major; later h (80..144 MB)
  u16* QH  = (u16*)(ws + 96 * MB);
  u16* KH  = (u16*)(ws + 112 * MB);
  u16* VT  = (u16*)(ws + 128 * MB);
  u16* ATT  = Qb;
  u16* XLN2 = Kb;
  u16* Hbuf = Vb;
  (void)in_sizes; (void)n_in; (void)out_size; (void)ws_size;

  // 1. weights fp32 -> bf16
  cvt_k<<<1024, 256, 0, stream>>>(qp, WQ, 262144);
  cvt_k<<<1024, 256, 0, stream>>>(kp, WK, 262144);
  cvt_k<<<1024, 256, 0, stream>>>(vp, WV, 262144);
  cvt_k<<<1024, 256, 0, stream>>>(op, WO, 262144);
  cvt_k<<<4096, 256, 0, stream>>>(w1, W1, 1048576);
  cvt_k<<<4096, 256, 0, stream>>>(w3, W3, 1048576);
  cvt_k<<<4096, 256, 0, stream>>>(w2, W2, 1048576);
  // 2. x_ln = rmsnorm(x, ln1)
  rmsnorm_k<<<8192, 256, 0, stream>>>(x, ln1, XLN);
  // 3. q/k/v projections (bt-form GEMMs)
  gemm_bt<0><<<dim3(8, 64), 256, 0, stream>>>(XLN, WQ, Qb, nullptr, nullptr, 8192, 1024, 1024);
  gemm_bt<0><<<dim3(8, 64), 256, 0, stream>>>(XLN, WK, Kb, nullptr, nullptr, 8192, 1024, 1024);
  gemm_bt<0><<<dim3(8, 64), 256, 0, stream>>>(XLN, WV, Vb, nullptr, nullptr, 8192, 1024, 1024);
  // 4. RoPE + head relayout
  rope_k<<<16384, 256, 0, stream>>>(Qb, QH, pos);
  rope_k<<<16384, 256, 0, stream>>>(Kb, KH, pos);
  // 5. v -> vT per head
  transv_k<<<dim3(32, 64), 256, 0, stream>>>(Vb, VT);
  // 6. causal flash attention
  attn_k<<<dim3(32, 64), 256, 0, stream>>>(QH, KH, VT, ATT);
  // 7. x2 = x + attn @ Wo^T  (fp32, into d_out)
  gemm_bt<1><<<dim3(8, 64), 256, 0, stream>>>(ATT, WO, nullptr, out, x, 8192, 1024, 1024);
  // 8. x_ln2 = rmsnorm(x2, ln2)
  rmsnorm_k<<<8192, 256, 0, stream>>>(out, ln2, XLN2);
  // 9. h = silu(x_ln2@W1^T) * (x_ln2@W3^T)
  ffn_gemm<<<dim3(32, 64), 256, 0, stream>>>(XLN2, W1, W3, Hbuf, 8192, 4096, 1024);
  // 10. out = x2 + h @ W2^T
  gemm_bt<1><<<dim3(8, 64), 256, 0, stream>>>(Hbuf, W2, nullptr, out, out, 8192, 1024, 4096);
}

// Round 2
// 743.985 us; speedup vs baseline: 1.1123x; 1.1123x over previous
//
#include <hip/hip_runtime.h>

// TransformerBlock on MI355X (gfx950) — round 1: 32x32x16 MFMA GEMMs,
// 2 waves/SIMD occupancy, fused QKV projection.
// B=4 S=2048 D=1024 H=16 DK=64 DFF=4096. fp32 in/out, bf16 tensor-core compute.

typedef unsigned short u16;
typedef __attribute__((ext_vector_type(8))) short short8;    // 8 bf16 (MFMA A/B frag)
typedef __attribute__((ext_vector_type(4))) float f32x4;     // 16x16 C/D frag
typedef __attribute__((ext_vector_type(16))) float f32x16;   // 32x32 C/D frag

#define MFMA16(a, b, c) __builtin_amdgcn_mfma_f32_16x16x32_bf16(a, b, c, 0, 0, 0)
#define MFMA32(a, b, c) __builtin_amdgcn_mfma_f32_32x32x16_bf16(a, b, c, 0, 0, 0)

__device__ __forceinline__ u16 f2b(float f) {
  union { float f; unsigned u; } x; x.f = f;
  unsigned r = x.u + 0x7FFFu + ((x.u >> 16) & 1u);   // RNE
  return (u16)(r >> 16);
}
__device__ __forceinline__ float b2f(u16 h) {
  union { unsigned u; float f; } x; x.u = ((unsigned)h) << 16;
  return x.f;
}
// async global->LDS, 16B per lane; LDS dest = wave-uniform base + lane*16.
__device__ __forceinline__ void async16(const void* g, void* l) {
  __builtin_amdgcn_global_load_lds(
      (const __attribute__((address_space(1))) void*)g,
      (__attribute__((address_space(3))) void*)l, 16, 0, 0);
}

// ---------------------------------------------------------------------------
// GEMM (bt-form): C[m,n] = sum_k A[m,k]*B[n,k].  A: MxK bf16, B: NxK bf16.
// 128x128 tile, BK=64, 4 waves (2x2 of 64x64), each 64x64 = 2x2 of 32x32x16.
// A-frag layout (32x32x16): A[m = lane&31][k = (lane>>5)*8 + j], j=0..7.
// C/D layout (m74/m101): col = lane&31, row = (reg&3) + 8*(reg>>2) + 4*(lane>>5).
// LDS chunk-XOR swizzle keeps ds_read_b128 conflict-free (R0: 0 conflicts).
// MODE 0: store bf16 C.  MODE 1: store fp32 C + residual R.
// ---------------------------------------------------------------------------
template <int MODE>
__global__ __launch_bounds__(256, 2) void gemm_bt(
    const u16* __restrict__ A, const u16* __restrict__ B,
    u16* __restrict__ Cb, float* __restrict__ Cf, const float* __restrict__ R,
    int M, int N, int K) {
  __shared__ __align__(16) u16 As[128 * 64];
  __shared__ __align__(16) u16 Bs[128 * 64];
  const int tid = threadIdx.x;
  const int l = tid & 63, w = tid >> 6;
  const int wr = w & 1, wc = w >> 1;
  const int lr = l & 31, lh = l >> 5;
  const size_t m0 = (size_t)blockIdx.y * 128, n0 = (size_t)blockIdx.x * 128;
  f32x16 acc[2][2] = {};
  for (int k0 = 0; k0 < K; k0 += 64) {
#pragma unroll
    for (int t = 0; t < 4; ++t) {  // 128x64 bf16 = 16KB = 1024 chunks of 16B, 4/thread
      int c = t * 256 + tid;
      int r = c >> 3;
      int gc = ((c & 7) ^ (r & 7)) << 3;
      async16(A + (m0 + r) * (size_t)K + k0 + gc, &As[c * 8]);
    }
#pragma unroll
    for (int t = 0; t < 4; ++t) {
      int c = t * 256 + tid;
      int r = c >> 3;
      int gc = ((c & 7) ^ (r & 7)) << 3;
      async16(B + (n0 + r) * (size_t)K + k0 + gc, &Bs[c * 8]);
    }
    __syncthreads();
#pragma unroll
    for (int c = 0; c < 4; ++c) {        // 4 chunks of K=16
      const int c8 = c * 2 + lh;         // 8-elt chunk index in the 64-wide row
      short8 af[2], bfr[2];
#pragma unroll
      for (int mi = 0; mi < 2; ++mi) {
        int r = wr * 64 + mi * 32 + lr;
        af[mi] = *(const short8*)&As[r * 64 + ((c8 ^ (r & 7)) << 3)];
      }
#pragma unroll
      for (int ni = 0; ni < 2; ++ni) {
        int r = wc * 64 + ni * 32 + lr;
        bfr[ni] = *(const short8*)&Bs[r * 64 + ((c8 ^ (r & 7)) << 3)];
      }
#pragma unroll
      for (int mi = 0; mi < 2; ++mi)
#pragma unroll
        for (int ni = 0; ni < 2; ++ni)
          acc[mi][ni] = MFMA32(af[mi], bfr[ni], acc[mi][ni]);
    }
    __syncthreads();
  }
#pragma unroll
  for (int mi = 0; mi < 2; ++mi)
#pragma unroll
    for (int ni = 0; ni < 2; ++ni) {
      size_t n = n0 + wc * 64 + ni * 32 + lr;
#pragma unroll
      for (int reg = 0; reg < 16; ++reg) {
        size_t m = m0 + wr * 64 + mi * 32 + (reg & 3) + 8 * (reg >> 2) + 4 * lh;
        float v = acc[mi][ni][reg];
        if (MODE == 0)
          Cb[m * (size_t)N + n] = f2b(v);
        else
          Cf[m * (size_t)N + n] = v + R[m * (size_t)N + n];
      }
    }
}

// ---------------------------------------------------------------------------
// Fused SwiGLU GEMM: h = silu(A@W1^T) * (A@W3^T), bf16 out. Dual accumulator.
// ---------------------------------------------------------------------------
__global__ __launch_bounds__(256, 2) void ffn_gemm(
    const u16* __restrict__ A, const u16* __restrict__ B1,
    const u16* __restrict__ B3, u16* __restrict__ Hout, int M, int N, int K) {
  __shared__ __align__(16) u16 As[128 * 64];
  __shared__ __align__(16) u16 B1s[128 * 64];
  __shared__ __align__(16) u16 B3s[128 * 64];
  const int tid = threadIdx.x;
  const int l = tid & 63, w = tid >> 6;
  const int wr = w & 1, wc = w >> 1;
  const int lr = l & 31, lh = l >> 5;
  const size_t m0 = (size_t)blockIdx.y * 128, n0 = (size_t)blockIdx.x * 128;
  f32x16 a1[2][2] = {}, a3[2][2] = {};
  for (int k0 = 0; k0 < K; k0 += 64) {
#pragma unroll
    for (int t = 0; t < 4; ++t) {
      int c = t * 256 + tid;
      int r = c >> 3;
      int gc = ((c & 7) ^ (r & 7)) << 3;
      async16(A + (m0 + r) * (size_t)K + k0 + gc, &As[c * 8]);
      async16(B1 + (n0 + r) * (size_t)K + k0 + gc, &B1s[c * 8]);
      async16(B3 + (n0 + r) * (size_t)K + k0 + gc, &B3s[c * 8]);
    }
    __syncthreads();
#pragma unroll
    for (int c = 0; c < 4; ++c) {
      const int c8 = c * 2 + lh;
      short8 af[2], b1f[2], b3f[2];
#pragma unroll
      for (int mi = 0; mi < 2; ++mi) {
        int r = wr * 64 + mi * 32 + lr;
        af[mi] = *(const short8*)&As[r * 64 + ((c8 ^ (r & 7)) << 3)];
      }
#pragma unroll
      for (int ni = 0; ni < 2; ++ni) {
        int r = wc * 64 + ni * 32 + lr;
        b1f[ni] = *(const short8*)&B1s[r * 64 + ((c8 ^ (r & 7)) << 3)];
        b3f[ni] = *(const short8*)&B3s[r * 64 + ((c8 ^ (r & 7)) << 3)];
      }
#pragma unroll
      for (int mi = 0; mi < 2; ++mi)
#pragma unroll
        for (int ni = 0; ni < 2; ++ni) {
          a1[mi][ni] = MFMA32(af[mi], b1f[ni], a1[mi][ni]);
          a3[mi][ni] = MFMA32(af[mi], b3f[ni], a3[mi][ni]);
        }
    }
    __syncthreads();
  }
#pragma unroll
  for (int mi = 0; mi < 2; ++mi)
#pragma unroll
    for (int ni = 0; ni < 2; ++ni) {
      size_t n = n0 + wc * 64 + ni * 32 + lr;
#pragma unroll
      for (int reg = 0; reg < 16; ++reg) {
        size_t m = m0 + wr * 64 + mi * 32 + (reg & 3) + 8 * (reg >> 2) + 4 * lh;
        float u = a1[mi][ni][reg];
        float g = u / (1.0f + __expf(-u));  // silu
        Hout[m * (size_t)N + n] = f2b(g * a3[mi][ni][reg]);
      }
    }
}

// ---------------------------------------------------------------------------
// Flash attention (causal) — unchanged from R0 (verified). 16x16x32 MFMA.
// ---------------------------------------------------------------------------
__global__ __launch_bounds__(256) void attn_k(
    const u16* __restrict__ qh, const u16* __restrict__ kh,
    const u16* __restrict__ vt, u16* __restrict__ aout) {
  __shared__ __align__(16) u16 Ks[64 * 64];
  __shared__ __align__(16) u16 Vs[64 * 64];
  __shared__ __align__(16) u16 Ps[4][16 * 72];
  const int tid = threadIdx.x;
  const int l = tid & 63, w = tid >> 6;
  const int lrow = l & 15, lq = l >> 4;
  const int q0 = blockIdx.x * 64;
  const int bh = blockIdx.y;
  const size_t base = (size_t)bh * (2048 * 64);

  short8 aq[2];
  const int qrow = q0 + w * 16 + lrow;
#pragma unroll
  for (int kk = 0; kk < 2; ++kk)
    aq[kk] = *(const short8*)(qh + base + (size_t)qrow * 64 + kk * 32 + lq * 8);

  f32x4 o[4] = {};
  float mI[4], lI[4];
#pragma unroll
  for (int r = 0; r < 4; ++r) { mI[r] = -1e30f; lI[r] = 0.0f; }

  for (int kv0 = 0; kv0 <= q0; kv0 += 64) {
#pragma unroll
    for (int t = 0; t < 2; ++t) {
      int c = t * 256 + tid;
      int r = c >> 3;
      int gc = ((c & 7) ^ (r & 7)) << 3;
      async16(kh + base + (size_t)(kv0 + r) * 64 + gc, &Ks[c * 8]);
      async16(vt + base + (size_t)r * 2048 + kv0 + gc, &Vs[c * 8]);
    }
    __syncthreads();
    f32x4 s[4] = {};
#pragma unroll
    for (int kk = 0; kk < 2; ++kk) {
      const int kc = kk * 4 + lq;
#pragma unroll
      for (int ni = 0; ni < 4; ++ni) {
        int r = ni * 16 + lrow;
        short8 bk = *(const short8*)&Ks[r * 64 + ((kc ^ (r & 7)) << 3)];
        s[ni] = MFMA16(aq[kk], bk, s[ni]);
      }
    }
    const bool diag = (kv0 == q0);
#pragma unroll
    for (int ni = 0; ni < 4; ++ni)
#pragma unroll
      for (int r = 0; r < 4; ++r) {
        float v = s[ni][r] * 0.125f;
        if (diag && (kv0 + ni * 16 + lrow > q0 + w * 16 + lq * 4 + r)) v = -1e30f;
        s[ni][r] = v;
      }
    float al[4];
#pragma unroll
    for (int r = 0; r < 4; ++r) {
      float mx = fmaxf(fmaxf(s[0][r], s[1][r]), fmaxf(s[2][r], s[3][r]));
#pragma unroll
      for (int d = 1; d < 16; d <<= 1) mx = fmaxf(mx, __shfl_xor(mx, d, 64));
      float mn = fmaxf(mI[r], mx);
      al[r] = __expf(mI[r] - mn);
      mI[r] = mn;
    }
    float rs[4] = {0.f, 0.f, 0.f, 0.f};
#pragma unroll
    for (int ni = 0; ni < 4; ++ni)
#pragma unroll
      for (int r = 0; r < 4; ++r) {
        float p = __expf(s[ni][r] - mI[r]);
        s[ni][r] = p;
        rs[r] += p;
      }
#pragma unroll
    for (int r = 0; r < 4; ++r) {
#pragma unroll
      for (int d = 1; d < 16; d <<= 1) rs[r] += __shfl_xor(rs[r], d, 64);
      lI[r] = lI[r] * al[r] + rs[r];
    }
#pragma unroll
    for (int ni = 0; ni < 4; ++ni)
#pragma unroll
      for (int r = 0; r < 4; ++r) o[ni][r] *= al[r];
#pragma unroll
    for (int ni = 0; ni < 4; ++ni)
#pragma unroll
      for (int r = 0; r < 4; ++r)
        Ps[w][(lq * 4 + r) * 72 + ni * 16 + lrow] = f2b(s[ni][r]);
    __syncthreads();
#pragma unroll
    for (int kk = 0; kk < 2; ++kk) {
      const int kc = kk * 4 + lq;
      short8 ap = *(const short8*)&Ps[w][lrow * 72 + kk * 32 + lq * 8];
#pragma unroll
      for (int ni = 0; ni < 4; ++ni) {
        int r = ni * 16 + lrow;
        short8 bv = *(const short8*)&Vs[r * 64 + ((kc ^ (r & 7)) << 3)];
        o[ni] = MFMA16(ap, bv, o[ni]);
      }
    }
    __syncthreads();
  }
  const int b = bh >> 4, h = bh & 15;
#pragma unroll
  for (int ni = 0; ni < 4; ++ni)
#pragma unroll
    for (int r = 0; r < 4; ++r) {
      int row = q0 + w * 16 + lq * 4 + r;
      int d = ni * 16 + lrow;
      aout[((size_t)(b * 2048 + row)) * 1024 + h * 64 + d] = f2b(o[ni][r] / lI[r]);
    }
}

// ---------------------------------------------------------------------------
// Elementwise helpers
// ---------------------------------------------------------------------------
__global__ __launch_bounds__(256) void rmsnorm_k(
    const float* __restrict__ x, const float* __restrict__ w, u16* __restrict__ out) {
  const int row = blockIdx.x;
  const int tid = threadIdx.x;
  const float4 v = ((const float4*)(x + (size_t)row * 1024))[tid];
  float ss = v.x * v.x + v.y * v.y + v.z * v.z + v.w * v.w;
#pragma unroll
  for (int d = 1; d < 64; d <<= 1) ss += __shfl_xor(ss, d, 64);
  __shared__ float red[4];
  if ((tid & 63) == 0) red[tid >> 6] = ss;
  __syncthreads();
  const float sc = rsqrtf((red[0] + red[1] + red[2] + red[3]) * (1.0f / 1024.0f) + 1e-5f);
  const float4 wv = ((const float4*)w)[tid];
  u16* o = out + (size_t)row * 1024 + tid * 4;
  o[0] = f2b(v.x * sc * wv.x);
  o[1] = f2b(v.y * sc * wv.y);
  o[2] = f2b(v.z * sc * wv.z);
  o[3] = f2b(v.w * sc * wv.w);
}

// RoPE for q AND k from the fused QKV buffer [8192][3072] -> QH/KH [b][h][s][64].
__global__ __launch_bounds__(256) void rope_k(
    const u16* __restrict__ qkv, u16* __restrict__ qh, u16* __restrict__ kh,
    const int* __restrict__ pos) {
  int idx = blockIdx.x * 256 + threadIdx.x;  // 8192 rows * 1024 pairs (512 q + 512 k)
  int pr = idx & 1023;
  int row = idx >> 10;
  int which = pr >> 9;  // 0=q, 1=k
  int p = pr & 511;
  int s = row & 2047, b = row >> 11;
  int h = p >> 5, i = p & 31;
  size_t si = (size_t)row * 3072 + which * 1024 + h * 64 + 2 * i;
  float xe = b2f(qkv[si]), xo = b2f(qkv[si + 1]);
  float inv = exp2f(-(float)(2 * i) * (13.287712379549449f / 64.0f));
  float ang = (float)pos[s] * inv;
  float sn, cs;
  __sincosf(ang, &sn, &cs);
  u16* dst = which ? kh : qh;
  size_t od = (((size_t)(b * 16 + h)) * 2048 + s) * 64 + 2 * i;
  dst[od] = f2b(xe * cs - xo * sn);
  dst[od + 1] = f2b(xe * sn + xo * cs);
}

// v (cols 2048..3071 of QKV) -> vT [b][h][d][s], 64x64 LDS tile transpose
__global__ __launch_bounds__(256) void transv_k(
    const u16* __restrict__ qkv, u16* __restrict__ vt) {
  __shared__ u16 t[64][65];
  const int bh = blockIdx.y, s0 = blockIdx.x * 64;
  const int b = bh >> 4, h = bh & 15;
  const int tid = threadIdx.x;
#pragma unroll
  for (int i = 0; i < 16; ++i) {
    int e = i * 256 + tid;
    int sl = e >> 6, d = e & 63;
    t[sl][d] = qkv[((size_t)(b * 2048 + s0 + sl)) * 3072 + 2048 + h * 64 + d];
  }
  __syncthreads();
#pragma unroll
  for (int i = 0; i < 16; ++i) {
    int e = i * 256 + tid;
    int d = e >> 6, sl = e & 63;
    vt[((size_t)(bh * 64 + d)) * 2048 + s0 + sl] = t[sl][d];
  }
}

__global__ __launch_bounds__(256) void cvt_k(
    const float* __restrict__ in, u16* __restrict__ out, int n4) {
  int i = blockIdx.x * 256 + threadIdx.x;
  if (i < n4) {
    float4 v = ((const float4*)in)[i];
    u16* o = out + (size_t)i * 4;
    o[0] = f2b(v.x); o[1] = f2b(v.y); o[2] = f2b(v.z); o[3] = f2b(v.w);
  }
}

// ---------------------------------------------------------------------------
extern "C" void kernel_launch(void* const* d_in, const int* in_sizes, int n_in,
                              void* d_out, int out_size, void* d_ws, size_t ws_size,
                              hipStream_t stream) {
  const float* x   = (const float*)d_in[0];
  const int*   pos = (const int*)d_in[1];
  const float* qp  = (const float*)d_in[2];
  const float* kp  = (const float*)d_in[3];
  const float* vp  = (const float*)d_in[4];
  const float* op  = (const float*)d_in[5];
  const float* w1  = (const float*)d_in[6];
  const float* w2  = (const float*)d_in[7];   // dict order: w2 before w3
  const float* w3  = (const float*)d_in[8];
  const float* ln1 = (const float*)d_in[9];
  const float* ln2 = (const float*)d_in[10];
  float* out = (float*)d_out;
  char* ws = (char*)d_ws;
  const size_t MB = 1024 * 1024;

  // workspace layout (144 MB, aliased lifetimes):
  u16* WQKV = (u16*)(ws + 0 * MB);    // [3072][1024] stacked q,k,v  (6 MB)
  u16* WO   = (u16*)(ws + 6 * MB);    // 2 MB
  u16* W1   = (u16*)(ws + 8 * MB);    // 8 MB
  u16* W3   = (u16*)(ws + 16 * MB);   // 8 MB
  u16* W2   = (u16*)(ws + 24 * MB);   // 8 MB
  u16* XLN  = (u16*)(ws + 32 * MB);   // 16 MB
  u16* QKV  = (u16*)(ws + 48 * MB);   // [8192][3072]  (48 MB, 48..96)
  u16* QH   = (u16*)(ws + 96 * MB);   // 16 MB
  u16* KH   = (u16*)(ws + 112 * MB);  // 16 MB
  u16* VT   = (u16*)(ws + 128 * MB);  // 16 MB
  u16* ATT  = (u16*)(ws + 48 * MB);   // reuses QKV (dead after rope/transv)
  u16* XLN2 = (u16*)(ws + 64 * MB);   // reuses QKV tail
  u16* Hbuf = (u16*)(ws + 80 * MB);   // 64 MB (80..144; VT dead by then)
  (void)in_sizes; (void)n_in; (void)out_size; (void)ws_size;

  // 1. weights fp32 -> bf16 (q,k,v stacked into WQKV)
  cvt_k<<<1024, 256, 0, stream>>>(qp, WQKV, 262144);
  cvt_k<<<1024, 256, 0, stream>>>(kp, WQKV + 1024 * 1024, 262144);
  cvt_k<<<1024, 256, 0, stream>>>(vp, WQKV + 2 * 1024 * 1024, 262144);
  cvt_k<<<1024, 256, 0, stream>>>(op, WO, 262144);
  cvt_k<<<4096, 256, 0, stream>>>(w1, W1, 1048576);
  cvt_k<<<4096, 256, 0, stream>>>(w3, W3, 1048576);
  cvt_k<<<4096, 256, 0, stream>>>(w2, W2, 1048576);
  // 2. x_ln = rmsnorm(x, ln1)
  rmsnorm_k<<<8192, 256, 0, stream>>>(x, ln1, XLN);
  // 3. fused qkv projection: QKV = x_ln @ [Wq;Wk;Wv]^T   (8192x3072x1024)
  gemm_bt<0><<<dim3(24, 64), 256, 0, stream>>>(XLN, WQKV, QKV, nullptr, nullptr, 8192, 3072, 1024);
  // 4. RoPE (q and k) + head relayout
  rope_k<<<32768, 256, 0, stream>>>(QKV, QH, KH, pos);
  // 5. v -> vT per head
  transv_k<<<dim3(32, 64), 256, 0, stream>>>(QKV, VT);
  // 6. causal flash attention
  attn_k<<<dim3(32, 64), 256, 0, stream>>>(QH, KH, VT, ATT);
  // 7. x2 = x + attn @ Wo^T  (fp32, into d_out)
  gemm_bt<1><<<dim3(8, 64), 256, 0, stream>>>(ATT, WO, nullptr, out, x, 8192, 1024, 1024);
  // 8. x_ln2 = rmsnorm(x2, ln2)
  rmsnorm_k<<<8192, 256, 0, stream>>>(out, ln2, XLN2);
  // 9. h = silu(x_ln2@W1^T) * (x_ln2@W3^T)
  ffn_gemm<<<dim3(32, 64), 256, 0, stream>>>(XLN2, W1, W3, Hbuf, 8192, 4096, 1024);
  // 10. out = x2 + h @ W2^T
  gemm_bt<1><<<dim3(8, 64), 256, 0, stream>>>(Hbuf, W2, nullptr, out, out, 8192, 1024, 4096);
}